// Round 1
// baseline (2009.702 us; speedup 1.0000x reference)
//
#include <hip/hip_runtime.h>
#include <cstdint>
#include <cstddef>

typedef short  short8  __attribute__((ext_vector_type(8)));
typedef float  float4v __attribute__((ext_vector_type(4)));

#define MFMA_B16(a,b,c) __builtin_amdgcn_mfma_f32_16x16x32_bf16(a,b,c,0,0,0)

static constexpr int B_  = 512;
static constexpr int T_  = 256;
static constexpr int DIN = 32;
static constexpr int H_  = 128;
static constexpr int TGT = 64;
static constexpr int G4  = 512;   // 4*H

// ---- workspace layout (bytes) ----
static constexpr size_t OFF_XFRAG = 0;                          // 32*256*64*16 = 8,388,608
static constexpr size_t OFF_EW0   = 8388608;                    // 32nt*5kb*64*16 = 163,840
static constexpr size_t OFF_EW1   = OFF_EW0 + 163840;           // 32*8*64*16 = 262,144
static constexpr size_t OFF_DW0   = OFF_EW1 + 262144;           // 163,840
static constexpr size_t OFF_DW1   = OFF_DW0 + 163840;           // 262,144
static constexpr size_t OFF_LIN   = OFF_DW1 + 262144;           // 2*4*64*16 = 8,192
static constexpr size_t OFF_BIAS  = OFF_LIN + 8192;             // 2080 floats = 8,320
static constexpr size_t WS_NEED   = OFF_BIAS + 8320;            // ~9.27 MB

__device__ __forceinline__ short f2bf(float f){
  unsigned u = __float_as_uint(f);
  unsigned r = (u + 0x7fffu + ((u>>16)&1u)) >> 16;   // RNE
  return (short)(r & 0xffffu);
}
__device__ __forceinline__ float sigm(float x){ return 1.f/(1.f+__expf(-x)); }
__device__ __forceinline__ float tanh_f(float x){
  float ax = fabsf(x);
  float e  = __expf(-2.f*ax);
  float t  = (1.f-e)/(1.f+e);
  return x < 0.f ? -t : t;
}

// ---------------- prep: x -> bf16 A-fragment tiles ----------------
// layout: xfrag[bblk][t][lane] : short8 ; b = bblk*16 + (lane&15), k = (lane>>4)*8 + j
__global__ void prep_x_kernel(const float* __restrict__ x, short8* __restrict__ xfrag){
  int i = blockIdx.x*256 + threadIdx.x;           // 32*256*64 = 524288 entries
  if (i >= 32*256*64) return;
  int l    = i & 63;
  int t    = (i >> 6) & 255;
  int bblk = i >> 14;
  int b    = bblk*16 + (l & 15);
  const float* src = x + ((size_t)(b*T_ + t))*DIN + ((l>>4)*8);
  short8 v;
  #pragma unroll
  for (int j=0;j<8;j++) v[j] = f2bf(src[j]);
  xfrag[i] = v;
}

// ---------------- prep: weights -> bf16 B-fragment tiles ----------------
// tile layout: [nt][kb][lane] short8 ; n = nt*16+(lane&15), k = kb*32 + (lane>>4)*8 + j
__device__ __forceinline__ void pack160(short8* __restrict__ dst,
                                        const float* __restrict__ Wih,   // (512,32)
                                        const float* __restrict__ Whh,   // (512,128)
                                        int e){
  int nt = e/320; int r = e%320; int kb = r/64; int l = r%64;
  int n  = nt*16 + (l&15);
  short8 v;
  #pragma unroll
  for (int j=0;j<8;j++){
    int k = kb*32 + (l>>4)*8 + j;
    float f = (k < 32) ? Wih[n*32 + k] : Whh[n*128 + (k-32)];
    v[j] = f2bf(f);
  }
  dst[e] = v;
}
__device__ __forceinline__ void pack256(short8* __restrict__ dst,
                                        const float* __restrict__ Wih,   // (512,128)
                                        const float* __restrict__ Whh,   // (512,128)
                                        int e){
  int nt = e/512; int r = e%512; int kb = r/64; int l = r%64;
  int n  = nt*16 + (l&15);
  short8 v;
  #pragma unroll
  for (int j=0;j<8;j++){
    int k = kb*32 + (l>>4)*8 + j;
    float f = (k < 128) ? Wih[n*128 + k] : Whh[n*128 + (k-128)];
    v[j] = f2bf(f);
  }
  dst[e] = v;
}

__global__ void prep_w_kernel(
    const float* __restrict__ eWih0, const float* __restrict__ eWhh0,
    const float* __restrict__ eWih1, const float* __restrict__ eWhh1,
    const float* __restrict__ dWih0, const float* __restrict__ dWhh0,
    const float* __restrict__ dWih1, const float* __restrict__ dWhh1,
    const float* __restrict__ linW,
    const float* __restrict__ eb0a, const float* __restrict__ eb0b,
    const float* __restrict__ eb1a, const float* __restrict__ eb1b,
    const float* __restrict__ db0a, const float* __restrict__ db0b,
    const float* __restrict__ db1a, const float* __restrict__ db1b,
    const float* __restrict__ linb,
    short8* __restrict__ encW0, short8* __restrict__ encW1,
    short8* __restrict__ decW0, short8* __restrict__ decW1,
    short8* __restrict__ linT,  float* __restrict__ biases)
{
  int i = blockIdx.x*256 + threadIdx.x;
  if (i < 10240)       { pack160(encW0, eWih0, eWhh0, i); }
  else if (i < 26624)  { pack256(encW1, eWih1, eWhh1, i-10240); }
  else if (i < 36864)  { pack160(decW0, dWih0, dWhh0, i-26624); }
  else if (i < 53248)  { pack256(decW1, dWih1, dWhh1, i-36864); }
  else if (i < 53760)  {
    int e = i - 53248;                       // lin: 2nt * 4kb * 64
    int nt = e/256; int r = e%256; int kb = r/64; int l = r%64;
    int n = nt*16 + (l&15);
    short8 v;
    #pragma unroll
    for (int j=0;j<8;j++){
      int k = kb*32 + (l>>4)*8 + j;          // k < 128
      v[j] = f2bf(linW[n*128 + k]);
    }
    linT[e] = v;
  }
  else if (i < 55840)  {
    int e = i - 53760;                       // 2080 bias entries
    float v;
    if      (e < 512)  v = eb0a[e]       + eb0b[e];
    else if (e < 1024) v = eb1a[e-512]   + eb1b[e-512];
    else if (e < 1536) v = db0a[e-1024]  + db0b[e-1024];
    else if (e < 2048) v = db1a[e-1536]  + db1b[e-1536];
    else               v = linb[e-2048];
    biases[e] = v;
  }
}

// ---------------- main fused persistent kernel ----------------
// grid = 32 blocks (16 batch rows each), 512 threads (8 waves).
// wave w owns gate n-tiles {4w..4w+3} (64 gates) and hidden slice k in [16w,16w+16).
__global__ __launch_bounds__(512, 1) void lstm_main_kernel(
    const short8* __restrict__ xfrag,
    const short8* __restrict__ encW0, const short8* __restrict__ encW1,
    const short8* __restrict__ decW0, const short8* __restrict__ decW1,
    const short8* __restrict__ linT,  const float* __restrict__ biases,
    float* __restrict__ out)
{
  __shared__ __align__(16) short Abuf[16][264];   // [row][k 0..255]+pad; k<128:h0, k>=128:h1
  __shared__ __align__(16) float Gbuf[512][20];   // [gate][row]+pad
  __shared__ __align__(16) short inpA[16][40];    // decoder input frame (32 cols)+pad

  const int tid = threadIdx.x;
  const int w   = tid >> 6;
  const int l   = tid & 63;
  const int col = l & 15;       // = A row (batch row) = D col (gate) lane field
  const int lq  = l >> 4;
  const int bblk = blockIdx.x;

  // zero h state
  for (int i = tid; i < 16*264; i += 512) ((short*)Abuf)[i] = 0;

  float c0[4] = {0.f,0.f,0.f,0.f};
  float c1[4] = {0.f,0.f,0.f,0.f};

  float bs0[4], bs1[4], bd0[4], bd1[4];
  #pragma unroll
  for (int i=0;i<4;i++){
    int g = (w*4+i)*16 + col;
    bs0[i] = biases[g];
    bs1[i] = biases[512  + g];
    bd0[i] = biases[1024 + g];
    bd1[i] = biases[1536 + g];
  }
  float blin_r = (w < 2) ? biases[2048 + w*16 + col] : 0.f;
  __syncthreads();

  auto ldsA = [&](int kcol) -> short8 {
    return *(const short8*)&Abuf[col][kcol + lq*8];
  };

  auto runL0 = [&](const short8* __restrict__ Wt, const float* bs, short8 a0){
    short8 ah[4];
    #pragma unroll
    for (int kb=0;kb<4;kb++) ah[kb] = ldsA(kb*32);
    #pragma unroll
    for (int i=0;i<4;i++){
      int nt = w*4 + i;
      const short8* wp = Wt + (size_t)(nt*5)*64 + l;
      float4v acc = {0.f,0.f,0.f,0.f};
      acc = MFMA_B16(a0,    wp[0],     acc);
      #pragma unroll
      for (int kb=0;kb<4;kb++) acc = MFMA_B16(ah[kb], wp[(kb+1)*64], acc);
      #pragma unroll
      for (int q=0;q<4;q++) acc[q] += bs[i];
      *(float4v*)&Gbuf[nt*16 + col][lq*4] = acc;
    }
  };

  auto runL1 = [&](const short8* __restrict__ Wt, const float* bs){
    short8 a[8];
    #pragma unroll
    for (int kb=0;kb<8;kb++) a[kb] = ldsA(kb*32);
    #pragma unroll
    for (int i=0;i<4;i++){
      int nt = w*4 + i;
      const short8* wp = Wt + (size_t)(nt*8)*64 + l;
      float4v acc = {0.f,0.f,0.f,0.f};
      #pragma unroll
      for (int kb=0;kb<8;kb++) acc = MFMA_B16(a[kb], wp[kb*64], acc);
      #pragma unroll
      for (int q=0;q<4;q++) acc[q] += bs[i];
      *(float4v*)&Gbuf[nt*16 + col][lq*4] = acc;
    }
  };

  auto update = [&](float* c, int kbase){
    #pragma unroll
    for (int q=0;q<4;q++){
      int k = 16*w + lq*4 + q;
      int r = col;
      float gi = Gbuf[k      ][r];
      float gf = Gbuf[128 + k][r];
      float gg = Gbuf[256 + k][r];
      float go = Gbuf[384 + k][r];
      float cc = sigm(gf)*c[q] + sigm(gi)*tanh_f(gg);
      c[q] = cc;
      float h = sigm(go)*tanh_f(cc);
      Abuf[r][kbase + k] = f2bf(h);
    }
  };

  // ---------------- encoder: 256 steps, both layers fused ----------------
  #pragma unroll 1
  for (int t = 0; t < T_; t++){
    short8 a0 = xfrag[(size_t)(bblk*T_ + t)*64 + l];
    runL0(encW0, bs0, a0);
    __syncthreads();
    update(c0, 0);
    __syncthreads();
    runL1(encW1, bs1);
    __syncthreads();
    update(c1, 128);
    __syncthreads();
  }

  // decoder initial input = x[:, -1, :]
  if (w == 0){
    short8 v = xfrag[(size_t)(bblk*T_ + (T_-1))*64 + l];
    *(short8*)&inpA[col][lq*8] = v;
  }
  __syncthreads();

  // ---------------- decoder: 64 steps ----------------
  #pragma unroll 1
  for (int td = 0; td < TGT; td++){
    short8 a0 = *(const short8*)&inpA[col][lq*8];
    runL0(decW0, bd0, a0);
    __syncthreads();
    update(c0, 0);
    __syncthreads();
    runL1(decW1, bd1);
    __syncthreads();
    update(c1, 128);
    __syncthreads();
    // projection: out = h1 @ lin_W^T + lin_b  (32 outputs -> waves 0,1)
    if (w < 2){
      short8 hf[4];
      #pragma unroll
      for (int kb=0;kb<4;kb++) hf[kb] = ldsA(128 + kb*32);
      const short8* wp = linT + (size_t)(w*4)*64 + l;
      float4v acc = {0.f,0.f,0.f,0.f};
      #pragma unroll
      for (int kb=0;kb<4;kb++) acc = MFMA_B16(hf[kb], wp[kb*64], acc);
      #pragma unroll
      for (int q=0;q<4;q++){
        float v = acc[q] + blin_r;
        int b = bblk*16 + lq*4 + q;
        out[((size_t)b*TGT + td)*DIN + (w*16 + col)] = v;
        inpA[lq*4 + q][w*16 + col] = f2bf(v);
      }
    }
    __syncthreads();
  }
}

// ---------------- host ----------------
extern "C" void kernel_launch(void* const* d_in, const int* in_sizes, int n_in,
                              void* d_out, int out_size, void* d_ws, size_t ws_size,
                              hipStream_t stream) {
  const float* x      = (const float*)d_in[0];
  // d_in[1] = target_len (compile-time 64)
  const float* eWih0  = (const float*)d_in[2];
  const float* eWhh0  = (const float*)d_in[3];
  const float* eb0a   = (const float*)d_in[4];
  const float* eb0b   = (const float*)d_in[5];
  const float* eWih1  = (const float*)d_in[6];
  const float* eWhh1  = (const float*)d_in[7];
  const float* eb1a   = (const float*)d_in[8];
  const float* eb1b   = (const float*)d_in[9];
  const float* dWih0  = (const float*)d_in[10];
  const float* dWhh0  = (const float*)d_in[11];
  const float* db0a   = (const float*)d_in[12];
  const float* db0b   = (const float*)d_in[13];
  const float* dWih1  = (const float*)d_in[14];
  const float* dWhh1  = (const float*)d_in[15];
  const float* db1a   = (const float*)d_in[16];
  const float* db1b   = (const float*)d_in[17];
  const float* linW   = (const float*)d_in[18];
  const float* linb   = (const float*)d_in[19];

  char* ws = (char*)d_ws;
  short8* xfrag = (short8*)(ws + OFF_XFRAG);
  short8* encW0 = (short8*)(ws + OFF_EW0);
  short8* encW1 = (short8*)(ws + OFF_EW1);
  short8* decW0 = (short8*)(ws + OFF_DW0);
  short8* decW1 = (short8*)(ws + OFF_DW1);
  short8* linT  = (short8*)(ws + OFF_LIN);
  float*  biases= (float*)(ws + OFF_BIAS);

  prep_x_kernel<<<2048, 256, 0, stream>>>(x, xfrag);
  prep_w_kernel<<<219, 256, 0, stream>>>(
      eWih0,eWhh0,eWih1,eWhh1,dWih0,dWhh0,dWih1,dWhh1,linW,
      eb0a,eb0b,eb1a,eb1b,db0a,db0b,db1a,db1b,linb,
      encW0,encW1,decW0,decW1,linT,biases);
  lstm_main_kernel<<<32, 512, 0, stream>>>(
      xfrag, encW0, encW1, decW0, decW1, linT, biases, (float*)d_out);
}

// Round 2
// 1215.860 us; speedup vs baseline: 1.6529x; 1.6529x over previous
//
#include <hip/hip_runtime.h>
#include <cstdint>
#include <cstddef>

typedef short  short8  __attribute__((ext_vector_type(8)));
typedef float  float4v __attribute__((ext_vector_type(4)));

#define MFMA_B16(a,b,c) __builtin_amdgcn_mfma_f32_16x16x32_bf16(a,b,c,0,0,0)

static constexpr int B_  = 512;
static constexpr int T_  = 256;
static constexpr int DIN = 32;
static constexpr int H_  = 128;
static constexpr int TGT = 64;

// ---- workspace layout (bytes) ----
static constexpr size_t OFF_XFRAG = 0;                          // 32*256*64*16 = 8,388,608
static constexpr size_t OFF_EW0   = 8388608;                    // 32nt*5kb*64*16 = 163,840
static constexpr size_t OFF_EW1   = OFF_EW0 + 163840;           // 32*8*64*16 = 262,144
static constexpr size_t OFF_DW0   = OFF_EW1 + 262144;           // 163,840
static constexpr size_t OFF_DW1   = OFF_DW0 + 163840;           // 262,144
static constexpr size_t OFF_LIN   = OFF_DW1 + 262144;           // 8,192
static constexpr size_t OFF_BIAS  = OFF_LIN + 8192;             // 2080 floats
static constexpr size_t WS_NEED   = OFF_BIAS + 8320;

__device__ __forceinline__ short f2bf(float f){
  unsigned u = __float_as_uint(f);
  unsigned r = (u + 0x7fffu + ((u>>16)&1u)) >> 16;   // RNE
  return (short)(r & 0xffffu);
}
__device__ __forceinline__ float fast_sigm(float x){
  float e = __expf(-x);
  return __builtin_amdgcn_rcpf(1.f + e);
}
__device__ __forceinline__ float fast_tanh(float x){
  float e = __expf(-2.f*x);                 // tanh = 2*sigm(2x)-1
  return __builtin_amdgcn_rcpf(1.f + e)*2.f - 1.f;
}

// ---------------- prep: x -> bf16 A-fragment tiles ----------------
__global__ void prep_x_kernel(const float* __restrict__ x, short8* __restrict__ xfrag){
  int i = blockIdx.x*256 + threadIdx.x;           // 32*256*64 entries
  if (i >= 32*256*64) return;
  int l    = i & 63;
  int t    = (i >> 6) & 255;
  int bblk = i >> 14;
  int b    = bblk*16 + (l & 15);
  const float* src = x + ((size_t)(b*T_ + t))*DIN + ((l>>4)*8);
  short8 v;
  #pragma unroll
  for (int j=0;j<8;j++) v[j] = f2bf(src[j]);
  xfrag[i] = v;
}

// ---------------- prep: weights -> bf16 B-fragment tiles ----------------
__device__ __forceinline__ void pack160(short8* __restrict__ dst,
                                        const float* __restrict__ Wih,   // (512,32)
                                        const float* __restrict__ Whh,   // (512,128)
                                        int e){
  int nt = e/320; int r = e%320; int kb = r/64; int l = r%64;
  int n  = nt*16 + (l&15);
  short8 v;
  #pragma unroll
  for (int j=0;j<8;j++){
    int k = kb*32 + (l>>4)*8 + j;
    float f = (k < 32) ? Wih[n*32 + k] : Whh[n*128 + (k-32)];
    v[j] = f2bf(f);
  }
  dst[e] = v;
}
__device__ __forceinline__ void pack256(short8* __restrict__ dst,
                                        const float* __restrict__ Wih,   // (512,128)
                                        const float* __restrict__ Whh,   // (512,128)
                                        int e){
  int nt = e/512; int r = e%512; int kb = r/64; int l = r%64;
  int n  = nt*16 + (l&15);
  short8 v;
  #pragma unroll
  for (int j=0;j<8;j++){
    int k = kb*32 + (l>>4)*8 + j;
    float f = (k < 128) ? Wih[n*128 + k] : Whh[n*128 + (k-128)];
    v[j] = f2bf(f);
  }
  dst[e] = v;
}

__global__ void prep_w_kernel(
    const float* __restrict__ eWih0, const float* __restrict__ eWhh0,
    const float* __restrict__ eWih1, const float* __restrict__ eWhh1,
    const float* __restrict__ dWih0, const float* __restrict__ dWhh0,
    const float* __restrict__ dWih1, const float* __restrict__ dWhh1,
    const float* __restrict__ linW,
    const float* __restrict__ eb0a, const float* __restrict__ eb0b,
    const float* __restrict__ eb1a, const float* __restrict__ eb1b,
    const float* __restrict__ db0a, const float* __restrict__ db0b,
    const float* __restrict__ db1a, const float* __restrict__ db1b,
    const float* __restrict__ linb,
    short8* __restrict__ encW0, short8* __restrict__ encW1,
    short8* __restrict__ decW0, short8* __restrict__ decW1,
    short8* __restrict__ linT,  float* __restrict__ biases)
{
  int i = blockIdx.x*256 + threadIdx.x;
  if (i < 10240)       { pack160(encW0, eWih0, eWhh0, i); }
  else if (i < 26624)  { pack256(encW1, eWih1, eWhh1, i-10240); }
  else if (i < 36864)  { pack160(decW0, dWih0, dWhh0, i-26624); }
  else if (i < 53248)  { pack256(decW1, dWih1, dWhh1, i-36864); }
  else if (i < 53760)  {
    int e = i - 53248;                       // lin: 2nt * 4kb * 64
    int nt = e/256; int r = e%256; int kb = r/64; int l = r%64;
    int n = nt*16 + (l&15);
    short8 v;
    #pragma unroll
    for (int j=0;j<8;j++){
      int k = kb*32 + (l>>4)*8 + j;          // k < 128
      v[j] = f2bf(linW[n*128 + k]);
    }
    linT[e] = v;
  }
  else if (i < 55840)  {
    int e = i - 53760;                       // 2080 bias entries
    float v;
    if      (e < 512)  v = eb0a[e]       + eb0b[e];
    else if (e < 1024) v = eb1a[e-512]   + eb1b[e-512];
    else if (e < 1536) v = db0a[e-1024]  + db0b[e-1024];
    else if (e < 2048) v = db1a[e-1536]  + db1b[e-1536];
    else               v = linb[e-2048];
    biases[e] = v;
  }
}

// ---------------- main fused persistent kernel ----------------
// 32 blocks (16 batch rows each) x 512 threads (8 waves).
// Wave w owns gate n-tiles {w, 8+w, 16+w, 24+w} = i,f,g,o gates of hidden
// slice [16w,16w+16) -> activations consume the wave's OWN accumulators
// (no gate LDS round-trip). Weights live in VGPRs (enc, then dec).
// h0/h1 double-buffered in LDS -> 2 barriers/step (3 in decoder).
__global__ __launch_bounds__(512, 2) void lstm_main_kernel(
    const short8* __restrict__ xfrag,
    const short8* __restrict__ encW0, const short8* __restrict__ encW1,
    const short8* __restrict__ decW0, const short8* __restrict__ decW1,
    const short8* __restrict__ linT,  const float* __restrict__ biases,
    float* __restrict__ out)
{
  // row pitch 520 shorts = 1040 B (16B-aligned rows, dword bank stride 4 -> 2-way = free)
  // k-layout per row: [0,128)=h0 buf0, [128,256)=h0 buf1, [256,384)=h1 buf0, [384,512)=h1 buf1
  __shared__ __align__(16) short Abuf[16][520];
  __shared__ __align__(16) short inpA[16][40];    // decoder input frame (32 cols)+pad

  const int tid  = threadIdx.x;
  const int w    = tid >> 6;
  const int l    = tid & 63;
  const int col  = l & 15;      // MFMA m (A) / n (B,D) lane field
  const int lq   = l >> 4;
  const int bblk = blockIdx.x;

  for (int i = tid; i < 16*520; i += 512) ((short*)Abuf)[i] = 0;

  // ---- persistent weight registers (encoder first) ----
  short8 W0r[4][5];   // L0: n-tile 8i+w, kb<5  (k: 32 input + 128 h)
  short8 W1r[4][8];   // L1: n-tile 8i+w, kb<8  (k: 128 h0 + 128 h1)
  #pragma unroll
  for (int i=0;i<4;i++){
    #pragma unroll
    for (int kb=0;kb<5;kb++) W0r[i][kb] = encW0[(size_t)(8*i+w)*320 + (size_t)kb*64 + l];
    #pragma unroll
    for (int kb=0;kb<8;kb++) W1r[i][kb] = encW1[(size_t)(8*i+w)*512 + (size_t)kb*64 + l];
  }
  float bs0[4], bs1[4];
  #pragma unroll
  for (int i=0;i<4;i++){
    bs0[i] = biases[       (8*i+w)*16 + col];
    bs1[i] = biases[512 +  (8*i+w)*16 + col];
  }

  float c0[4] = {0.f,0.f,0.f,0.f};
  float c1[4] = {0.f,0.f,0.f,0.f};

  const short8* xf = xfrag + (size_t)bblk*T_*64 + l;
  short8 a0 = xf[0];
  __syncthreads();

  // ---------------- encoder: 256 steps ----------------
  #pragma unroll 2
  for (int t = 0; t < T_; t++){
    const int h0r = (t & 1) * 128;
    const int h0w = 128 - h0r;
    const int h1r = 256 + h0r;
    const int h1w = 256 + h0w;

    // ---- phase 1: layer 0 ----
    short8 ah[4];
    #pragma unroll
    for (int kb=0;kb<4;kb++) ah[kb] = *(const short8*)&Abuf[col][h0r + kb*32 + lq*8];
    float4v acc0[4];
    #pragma unroll
    for (int i=0;i<4;i++){
      float4v a = {bs0[i],bs0[i],bs0[i],bs0[i]};
      a = MFMA_B16(a0, W0r[i][0], a);
      #pragma unroll
      for (int kb=0;kb<4;kb++) a = MFMA_B16(ah[kb], W0r[i][kb+1], a);
      acc0[i] = a;
    }
    short8 a0n = xf[(size_t)((t+1 < T_) ? t+1 : t)*64];   // prefetch next frame
    #pragma unroll
    for (int q=0;q<4;q++){
      float cc = fast_sigm(acc0[1][q])*c0[q] + fast_sigm(acc0[0][q])*fast_tanh(acc0[2][q]);
      c0[q] = cc;
      Abuf[lq*4+q][h0w + 16*w + col] = f2bf(fast_sigm(acc0[3][q])*fast_tanh(cc));
    }
    a0 = a0n;
    __syncthreads();

    // ---- phase 2: layer 1 ----
    short8 a1[8];
    #pragma unroll
    for (int kb=0;kb<4;kb++) a1[kb]   = *(const short8*)&Abuf[col][h0w + kb*32 + lq*8];
    #pragma unroll
    for (int kb=0;kb<4;kb++) a1[4+kb] = *(const short8*)&Abuf[col][h1r + kb*32 + lq*8];
    float4v acc1[4];
    #pragma unroll
    for (int i=0;i<4;i++){
      float4v a = {bs1[i],bs1[i],bs1[i],bs1[i]};
      #pragma unroll
      for (int kb=0;kb<8;kb++) a = MFMA_B16(a1[kb], W1r[i][kb], a);
      acc1[i] = a;
    }
    #pragma unroll
    for (int q=0;q<4;q++){
      float cc = fast_sigm(acc1[1][q])*c1[q] + fast_sigm(acc1[0][q])*fast_tanh(acc1[2][q]);
      c1[q] = cc;
      Abuf[lq*4+q][h1w + 16*w + col] = f2bf(fast_sigm(acc1[3][q])*fast_tanh(cc));
    }
    __syncthreads();
  }

  // ---- swap weights to decoder ----
  #pragma unroll
  for (int i=0;i<4;i++){
    #pragma unroll
    for (int kb=0;kb<5;kb++) W0r[i][kb] = decW0[(size_t)(8*i+w)*320 + (size_t)kb*64 + l];
    #pragma unroll
    for (int kb=0;kb<8;kb++) W1r[i][kb] = decW1[(size_t)(8*i+w)*512 + (size_t)kb*64 + l];
    bs0[i] = biases[1024 + (8*i+w)*16 + col];
    bs1[i] = biases[1536 + (8*i+w)*16 + col];
  }
  short8 WLr[4];
  float blin = 0.f;
  if (w < 2){
    #pragma unroll
    for (int kb=0;kb<4;kb++) WLr[kb] = linT[(size_t)(w*4+kb)*64 + l];
    blin = biases[2048 + w*16 + col];
  }
  if (w == 0){
    *(short8*)&inpA[col][lq*8] = xf[(size_t)(T_-1)*64];   // dec input 0 = x[:,-1,:]
  }
  __syncthreads();

  // ---------------- decoder: 64 steps ----------------
  #pragma unroll 2
  for (int td = 0; td < TGT; td++){
    const int h0r = (td & 1) * 128;     // parity continues: 256+td has same parity as td
    const int h0w = 128 - h0r;
    const int h1r = 256 + h0r;
    const int h1w = 256 + h0w;

    // ---- phase 1: layer 0 ----
    short8 a0d = *(const short8*)&inpA[col][lq*8];
    short8 ah[4];
    #pragma unroll
    for (int kb=0;kb<4;kb++) ah[kb] = *(const short8*)&Abuf[col][h0r + kb*32 + lq*8];
    float4v acc0[4];
    #pragma unroll
    for (int i=0;i<4;i++){
      float4v a = {bs0[i],bs0[i],bs0[i],bs0[i]};
      a = MFMA_B16(a0d, W0r[i][0], a);
      #pragma unroll
      for (int kb=0;kb<4;kb++) a = MFMA_B16(ah[kb], W0r[i][kb+1], a);
      acc0[i] = a;
    }
    #pragma unroll
    for (int q=0;q<4;q++){
      float cc = fast_sigm(acc0[1][q])*c0[q] + fast_sigm(acc0[0][q])*fast_tanh(acc0[2][q]);
      c0[q] = cc;
      Abuf[lq*4+q][h0w + 16*w + col] = f2bf(fast_sigm(acc0[3][q])*fast_tanh(cc));
    }
    __syncthreads();

    // ---- phase 2: layer 1 ----
    short8 a1[8];
    #pragma unroll
    for (int kb=0;kb<4;kb++) a1[kb]   = *(const short8*)&Abuf[col][h0w + kb*32 + lq*8];
    #pragma unroll
    for (int kb=0;kb<4;kb++) a1[4+kb] = *(const short8*)&Abuf[col][h1r + kb*32 + lq*8];
    float4v acc1[4];
    #pragma unroll
    for (int i=0;i<4;i++){
      float4v a = {bs1[i],bs1[i],bs1[i],bs1[i]};
      #pragma unroll
      for (int kb=0;kb<8;kb++) a = MFMA_B16(a1[kb], W1r[i][kb], a);
      acc1[i] = a;
    }
    #pragma unroll
    for (int q=0;q<4;q++){
      float cc = fast_sigm(acc1[1][q])*c1[q] + fast_sigm(acc1[0][q])*fast_tanh(acc1[2][q]);
      c1[q] = cc;
      Abuf[lq*4+q][h1w + 16*w + col] = f2bf(fast_sigm(acc1[3][q])*fast_tanh(cc));
    }
    __syncthreads();

    // ---- phase 3: projection + feedback ----
    if (w < 2){
      short8 hf[4];
      #pragma unroll
      for (int kb=0;kb<4;kb++) hf[kb] = *(const short8*)&Abuf[col][h1w + kb*32 + lq*8];
      float4v a = {blin,blin,blin,blin};
      #pragma unroll
      for (int kb=0;kb<4;kb++) a = MFMA_B16(hf[kb], WLr[kb], a);
      #pragma unroll
      for (int q=0;q<4;q++){
        float v = a[q];
        int b = bblk*16 + lq*4 + q;
        out[((size_t)b*TGT + td)*DIN + (w*16 + col)] = v;
        inpA[lq*4+q][w*16 + col] = f2bf(v);
      }
    }
    __syncthreads();
  }
}

// ---------------- host ----------------
extern "C" void kernel_launch(void* const* d_in, const int* in_sizes, int n_in,
                              void* d_out, int out_size, void* d_ws, size_t ws_size,
                              hipStream_t stream) {
  const float* x      = (const float*)d_in[0];
  const float* eWih0  = (const float*)d_in[2];
  const float* eWhh0  = (const float*)d_in[3];
  const float* eb0a   = (const float*)d_in[4];
  const float* eb0b   = (const float*)d_in[5];
  const float* eWih1  = (const float*)d_in[6];
  const float* eWhh1  = (const float*)d_in[7];
  const float* eb1a   = (const float*)d_in[8];
  const float* eb1b   = (const float*)d_in[9];
  const float* dWih0  = (const float*)d_in[10];
  const float* dWhh0  = (const float*)d_in[11];
  const float* db0a   = (const float*)d_in[12];
  const float* db0b   = (const float*)d_in[13];
  const float* dWih1  = (const float*)d_in[14];
  const float* dWhh1  = (const float*)d_in[15];
  const float* db1a   = (const float*)d_in[16];
  const float* db1b   = (const float*)d_in[17];
  const float* linW   = (const float*)d_in[18];
  const float* linb   = (const float*)d_in[19];

  char* ws = (char*)d_ws;
  short8* xfrag = (short8*)(ws + OFF_XFRAG);
  short8* encW0 = (short8*)(ws + OFF_EW0);
  short8* encW1 = (short8*)(ws + OFF_EW1);
  short8* decW0 = (short8*)(ws + OFF_DW0);
  short8* decW1 = (short8*)(ws + OFF_DW1);
  short8* linT  = (short8*)(ws + OFF_LIN);
  float*  biases= (float*)(ws + OFF_BIAS);

  prep_x_kernel<<<2048, 256, 0, stream>>>(x, xfrag);
  prep_w_kernel<<<219, 256, 0, stream>>>(
      eWih0,eWhh0,eWih1,eWhh1,dWih0,dWhh0,dWih1,dWhh1,linW,
      eb0a,eb0b,eb1a,eb1b,db0a,db0b,db1a,db1b,linb,
      encW0,encW1,decW0,decW1,linT,biases);
  lstm_main_kernel<<<32, 512, 0, stream>>>(
      xfrag, encW0, encW1, decW0, decW1, linT, biases, (float*)d_out);
}